// Round 8
// baseline (2559.573 us; speedup 1.0000x reference)
//
#include <hip/hip_runtime.h>
#include <stdint.h>
#include <math.h>

#define N_ROWS 8192
#define N_TOK  8192
#define N_DIM  512
#define N_SAMP 10
#define GK     1536   // 3 * 512, bf16x2 split zones

typedef __attribute__((ext_vector_type(8))) short bf16x8_t;
typedef __attribute__((ext_vector_type(4))) float f32x4_t;

// ---------------- JAX threefry2x32 (exact; rotl forced to 1-op alignbit) ----------------
__host__ __device__ __forceinline__ void tf2x32(uint32_t ks0, uint32_t ks1,
                                                uint32_t& x0, uint32_t& x1) {
  uint32_t ks2 = ks0 ^ ks1 ^ 0x1BD11BDAu;
  x0 += ks0; x1 += ks1;
#define TF_ROUND(r) { x0 += x1; x1 = __builtin_rotateleft32(x1, r); x1 ^= x0; }
  TF_ROUND(13) TF_ROUND(15) TF_ROUND(26) TF_ROUND(6)
  x0 += ks1; x1 += ks2 + 1u;
  TF_ROUND(17) TF_ROUND(29) TF_ROUND(16) TF_ROUND(24)
  x0 += ks2; x1 += ks0 + 2u;
  TF_ROUND(13) TF_ROUND(15) TF_ROUND(26) TF_ROUND(6)
  x0 += ks0; x1 += ks1 + 3u;
  TF_ROUND(17) TF_ROUND(29) TF_ROUND(16) TF_ROUND(24)
  x0 += ks1; x1 += ks2 + 4u;
  TF_ROUND(13) TF_ROUND(15) TF_ROUND(26) TF_ROUND(6)
  x0 += ks2; x1 += ks0 + 5u;
#undef TF_ROUND
}

__device__ __forceinline__ unsigned short f2bf_rne(float f) {
  uint32_t u = __float_as_uint(f);
  uint32_t r = (u + 0x7fffu + ((u >> 16) & 1u)) >> 16;
  return (unsigned short)r;
}
__device__ __forceinline__ float bf2f(unsigned short h) {
  return __uint_as_float((uint32_t)h << 16);
}

__device__ __forceinline__ unsigned long long shfl_xor_u64(unsigned long long v, int off) {
  uint32_t lo = (uint32_t)v, hi = (uint32_t)(v >> 32);
  lo = (uint32_t)__shfl_xor((int)lo, off, 64);
  hi = (uint32_t)__shfl_xor((int)hi, off, 64);
  return ((unsigned long long)hi << 32) | lo;
}

// ---------------- opaque accept body: publishes immediately, returns new screen ----------
// Arithmetic identical to the proven r6/v3 accept path. atomicMin is
// order-independent and any observed wv yields a conservative screen, so
// immediate publication is exact. noinline + the atomicMin (memory side
// effect) make the body non-speculatable.
__device__ __attribute__((noinline)) uint32_t accept_publish(
    uint32_t bits, float Ek, uint32_t kglob, uint32_t th,
    unsigned long long* __restrict__ cp) {
  const float tiny = 1.1754943508222875e-38f;
  float u = __uint_as_float(0x3f800000u | (bits >> 9)) - 1.0f;
  u = fmaxf(u, tiny);
  float wv = -logf(u) * Ek;                    // exact r6 arithmetic
  unsigned long long p = ((unsigned long long)__float_as_uint(wv) << 32) | kglob;
  atomicMin(cp, p);
  float ut = expf(-wv) * 0.999999f;            // conservative (Ek>=1)
  uint32_t nt = ((uint32_t)(ut * 8388608.0f)) << 9;
  return (nt > th) ? nt : th;                  // never loosen
}

// ---------------- row sum-of-squares ----------------
__global__ __launch_bounds__(256) void rownorm_kernel(const float* __restrict__ M,
                                                      float* __restrict__ out) {
  int lane = threadIdx.x & 63;
  int row = (int)((blockIdx.x * blockDim.x + threadIdx.x) >> 6);
  const float* p = M + (size_t)row * N_DIM;
  float acc = 0.f;
#pragma unroll
  for (int d = 0; d < N_DIM; d += 64) {
    float v = p[d + lane];
    acc = fmaf(v, v, acc);
  }
#pragma unroll
  for (int off = 32; off; off >>= 1) acc += __shfl_xor(acc, off, 64);
  if (lane == 0) out[row] = acc;
}

// ---------------- state init ----------------
__global__ __launch_bounds__(256) void init_champ_kernel(unsigned long long* __restrict__ c) {
  int i = blockIdx.x * 256 + threadIdx.x;
  if (i < N_ROWS * N_SAMP) c[i] = 0xFFFFFFFFFFFFFFFFULL;
}

__global__ __launch_bounds__(256) void init_state_kernel(float* __restrict__ rmin,
                                                         int* __restrict__ ridx) {
  int i = blockIdx.x * 256 + threadIdx.x;
  if (i < N_ROWS * N_SAMP) { rmin[i] = INFINITY; ridx[i] = 0; }
}

// ---------------- bf16x2 split ----------------
__global__ __launch_bounds__(256) void split_kernel(const float* __restrict__ src,
                                                    unsigned short* __restrict__ dst,
                                                    int mode) {
  int t = blockIdx.x * 256 + threadIdx.x;
  int row = t >> 7;
  int c = (t & 127) << 2;
  float4 v = *(const float4*)(src + (size_t)row * N_DIM + c);
  ushort4 hi, lo;
  hi.x = f2bf_rne(v.x); lo.x = f2bf_rne(v.x - bf2f(hi.x));
  hi.y = f2bf_rne(v.y); lo.y = f2bf_rne(v.y - bf2f(hi.y));
  hi.z = f2bf_rne(v.z); lo.z = f2bf_rne(v.z - bf2f(hi.z));
  hi.w = f2bf_rne(v.w); lo.w = f2bf_rne(v.w - bf2f(hi.w));
  unsigned short* base = dst + (size_t)row * GK;
  *(ushort4*)(base + c) = hi;
  if (mode == 0) {
    *(ushort4*)(base + 512 + c) = lo;
    *(ushort4*)(base + 1024 + c) = hi;
  } else {
    *(ushort4*)(base + 512 + c) = hi;
    *(ushort4*)(base + 1024 + c) = lo;
  }
}

__device__ __forceinline__ void async_cp16(const void* g, void* l) {
  __builtin_amdgcn_global_load_lds((const __attribute__((address_space(1))) void*)g,
                                   (__attribute__((address_space(3))) void*)l, 16, 0, 0);
}

// ---------------- FUSED bf16 MFMA GEMM + multinomial sampler, 2-pass Et ----------------
// v8 = v7 structure (2-pass 64x128 Et, 32 KB LDS) with two fixes:
//  (1) NO launch_bounds wave cap: v7's (256,4) forced arch-VGPR to 64 (acc
//      needs 64 AGPRs; 4 waves/SIMD caps VGPR+AGPR at 128) -> 550 MB scratch
//      spills. Plain 256: VGPR ~92+64 AGPR -> 3 blocks/CU (LDS would allow 5),
//      37.5% occupancy, zero spill.
//  (2) accept body behind a UNIFORM ballot guard + noinline call w/ atomicMin.
//      v3-v7 instruction accounting shows the ~65-op accept body issued on
//      every one of 671M evals (VALU instrs ~1.8G vs 0.79G scan floor):
//      exec-masked flattening executes divergent bodies/calls regardless of
//      per-lane `if`s. A branch on the SCALAR condition ballot!=0 must be a
//      real s_cbranch_scc and cannot be flattened around a call.
// Hot loop: threefry + cmp + ballot (~77 ops/eval). Exactness unchanged:
// skip only when no lane passes the screen; atomicMin order-independent.
__global__ __launch_bounds__(256) void fused_gemm_sample_kernel(
    const unsigned short* __restrict__ A2, const unsigned short* __restrict__ B2,
    const float* __restrict__ xx, const float* __restrict__ ee,
    unsigned long long* __restrict__ champ, uint32_t k0, uint32_t k1) {
  __shared__ __align__(16) unsigned char smem[32768];
  unsigned short* As = (unsigned short*)smem;              // 128*64 ushort = 16 KB
  unsigned short* Bs = (unsigned short*)(smem + 16384);    // 16 KB
  float* Et = (float*)smem;                                // 64*128 f32 = 32 KB (reuse)
  int tid = threadIdx.x;
  int w = tid >> 6, l = tid & 63;

  int bid = blockIdx.y * gridDim.x + blockIdx.x;
  int by = bid & 63;   // row-block: fast -> spreads rows across XCDs
  int bx = bid >> 6;   // col-block: slow -> generations, screens tighten

  int row0 = by * 128;
  int col0 = bx * 128;
  int wm = (w & 1) * 64, wn = (w >> 1) * 64;
  int quad = l >> 4, r15 = l & 15;

  f32x4_t acc[4][4];
#pragma unroll
  for (int i = 0; i < 4; ++i)
#pragma unroll
    for (int j = 0; j < 4; ++j) acc[i][j] = (f32x4_t){0.f, 0.f, 0.f, 0.f};

  int srow[4], skc[4];
#pragma unroll
  for (int r = 0; r < 4; ++r) {
    int c = tid + 256 * r;
    srow[r] = c >> 3;
    skc[r] = (c & 7) ^ (srow[r] & 7);
  }

  for (int kt = 0; kt < GK; kt += 64) {
#pragma unroll
    for (int r = 0; r < 4; ++r) {
      int c = tid + 256 * r;
      async_cp16(A2 + (size_t)(row0 + srow[r]) * GK + kt + skc[r] * 8, As + c * 8);
      async_cp16(B2 + (size_t)(col0 + srow[r]) * GK + kt + skc[r] * 8, Bs + c * 8);
    }
    __syncthreads();

#pragma unroll
    for (int kk2 = 0; kk2 < 2; ++kk2) {
      bf16x8_t af[4], bf[4];
#pragma unroll
      for (int i = 0; i < 4; ++i) {
        int row = wm + i * 16 + r15;
        int qc = (kk2 * 4 + quad) ^ (r15 & 7);
        af[i] = *(const bf16x8_t*)&As[row * 64 + qc * 8];
      }
#pragma unroll
      for (int j = 0; j < 4; ++j) {
        int row = wn + j * 16 + r15;
        int qc = (kk2 * 4 + quad) ^ (r15 & 7);
        bf[j] = *(const bf16x8_t*)&Bs[row * 64 + qc * 8];
      }
#pragma unroll
      for (int i = 0; i < 4; ++i)
#pragma unroll
        for (int j = 0; j < 4; ++j)
          acc[i][j] = __builtin_amdgcn_mfma_f32_16x16x32_bf16(af[i], bf[j], acc[i][j], 0, 0, 0);
    }
    __syncthreads();
  }

  const float inv_nt = 1.f / 8192.f;
  float eev[4];
#pragma unroll
  for (int j = 0; j < 4; ++j) eev[j] = ee[col0 + wn + j * 16 + r15];

#pragma unroll 1
  for (int p = 0; p < 2; ++p) {
    // ---- write Et half: rows [p*64, p*64+64), owned by waves (w&1)==p ----
    if ((w & 1) == p) {
#pragma unroll
      for (int i = 0; i < 4; ++i) {
#pragma unroll
        for (int r = 0; r < 4; ++r) {
          int lr = i * 16 + quad * 4 + r;          // row within half
          float xxv = xx[row0 + p * 64 + lr];
          int mxr = lr & 31;
#pragma unroll
          for (int j = 0; j < 4; ++j) {
            int col = wn + j * 16 + r15;
            float dist = (xxv + eev[j] - 2.0f * acc[i][j][r]) * inv_nt;
            Et[lr * 128 + (col ^ mxr)] = expf(dist);   // bit-identical to r6 E value
          }
        }
      }
    }
    __syncthreads();

    // ---- scan half: thread = (row, col-quarter); 32 cols x 10 samples ----
    int lr = tid >> 2;                     // 0..63 row within half
    int q4 = tid & 3;                      // col quarter
    int grow = row0 + p * 64 + lr;
    unsigned long long* cg = champ + (size_t)grow * N_SAMP;
    uint32_t th[N_SAMP];
#pragma unroll
    for (int s = 0; s < N_SAMP; ++s) {
      unsigned long long c = cg[s];        // snapshot: stale/torn only -> looser screen
      uint32_t hi = (uint32_t)(c >> 32);
      uint32_t t = 0u;
      if (hi < 0x7F800000u) {
        float ut = expf(-__uint_as_float(hi)) * 0.999999f;
        t = ((uint32_t)(ut * 8388608.0f)) << 9;
      }
      th[s] = t;
    }
    uint32_t row_c = (uint32_t)grow * 81920u;
    int mxr = lr & 31;
    const float* Erow = Et + lr * 128;
    int colb = q4 * 32;

    for (int c = 0; c < 32; ++c) {
      int col = colb + c;
      float Ek = Erow[col ^ mxr];          // swizzled read, ~conflict-free
      uint32_t kglob = (uint32_t)(col0 + col);
      uint32_t base_c = row_c + kglob;
#pragma unroll
      for (int s = 0; s < N_SAMP; ++s) {
        uint32_t x0 = 0u, x1 = base_c + (uint32_t)s * 8192u;
        tf2x32(k0, k1, x0, x1);
        uint32_t bits = x0 ^ x1;
        // uniform scalar guard: s_cbranch, cannot be exec-flattened around call
        if (__ballot(bits >= th[s]) != 0ULL) {
          if (bits >= th[s])               // exec-masked rare call
            th[s] = accept_publish(bits, Ek, kglob, th[s], &cg[s]);
        }
      }
    }
    __syncthreads();                       // Et reused by next pass
  }
}

// ---------------- fp32 NT GEMM (fallback, r6-proven) with E-epilogue ----------------
__global__ __launch_bounds__(256) void gemm_nt_kernel(const float* __restrict__ A,
                                                      const float* __restrict__ B,
                                                      const float* __restrict__ xx,
                                                      const float* __restrict__ ee,
                                                      float* __restrict__ E,
                                                      int ks, int KC) {
  __shared__ __align__(16) float Asf[32][68];
  __shared__ __align__(16) float Bsf[32][68];
  int tid = threadIdx.x;
  int row0 = blockIdx.y * 64;
  int colB0 = blockIdx.x * 64 + ks;
  int tx = tid & 15, ty = tid >> 4;
  float acc[4][4] = {};
  for (int d0 = 0; d0 < N_DIM; d0 += 32) {
#pragma unroll
    for (int r = 0; r < 2; ++r) {
      int c = tid + 256 * r;
      int m = c >> 3;
      int dv = (c & 7) << 2;
      const float4 va = *(const float4*)(A + (size_t)(row0 + m) * N_DIM + d0 + dv);
      Asf[dv + 0][m] = va.x; Asf[dv + 1][m] = va.y;
      Asf[dv + 2][m] = va.z; Asf[dv + 3][m] = va.w;
      const float4 vb = *(const float4*)(B + (size_t)(colB0 + m) * N_DIM + d0 + dv);
      Bsf[dv + 0][m] = vb.x; Bsf[dv + 1][m] = vb.y;
      Bsf[dv + 2][m] = vb.z; Bsf[dv + 3][m] = vb.w;
    }
    __syncthreads();
#pragma unroll
    for (int dd = 0; dd < 32; ++dd) {
      float4 a4 = *(const float4*)&Asf[dd][ty << 2];
      float4 b4 = *(const float4*)&Bsf[dd][tx << 2];
      float av[4] = {a4.x, a4.y, a4.z, a4.w};
      float bv[4] = {b4.x, b4.y, b4.z, b4.w};
#pragma unroll
      for (int i = 0; i < 4; ++i)
#pragma unroll
        for (int j = 0; j < 4; ++j)
          acc[i][j] = fmaf(av[i], bv[j], acc[i][j]);
    }
    __syncthreads();
  }
  const float inv_nt = 1.f / 8192.f;
  int colC0 = blockIdx.x * 64;
  float eev[4];
#pragma unroll
  for (int j = 0; j < 4; ++j) eev[j] = ee[ks + colC0 + (tx << 2) + j];
#pragma unroll
  for (int i = 0; i < 4; ++i) {
    int grow = row0 + (ty << 2) + i;
    float xxv = xx[grow];
    float4 v;
    v.x = expf((xxv + eev[0] - 2.0f * acc[i][0]) * inv_nt);
    v.y = expf((xxv + eev[1] - 2.0f * acc[i][1]) * inv_nt);
    v.z = expf((xxv + eev[2] - 2.0f * acc[i][2]) * inv_nt);
    v.w = expf((xxv + eev[3] - 2.0f * acc[i][3]) * inv_nt);
    *(float4*)(E + (size_t)grow * KC + colC0 + (tx << 2)) = v;
  }
}

// ---------------- fallback sampler: wave-shared champion + bits screen ----------------
__global__ __launch_bounds__(256) void sample_kernel(const float* __restrict__ E,
                                                     float* __restrict__ rmin,
                                                     int* __restrict__ ridx,
                                                     int ks, int KC,
                                                     uint32_t k0, uint32_t k1) {
  int lane = threadIdx.x & 63;
  int row = (int)((blockIdx.x * blockDim.x + threadIdx.x) >> 6);
  unsigned long long champ[N_SAMP];
  uint32_t th[N_SAMP];
#pragma unroll
  for (int s = 0; s < N_SAMP; ++s) { champ[s] = 0xFFFFFFFFFFFFFFFFULL; th[s] = 0u; }
  const float tiny = 1.1754943508222875e-38f;
  uint32_t row_c = (uint32_t)row * 81920u;
  const float* Erow = E + (size_t)row * KC;

  float Ek = Erow[lane];
  for (int kk = lane; kk < KC; kk += 64) {
    int nk = (kk + 64 < KC) ? kk + 64 : kk;
    float Ekn = Erow[nk];
    uint32_t k = (uint32_t)(ks + kk);
    uint32_t base_c = row_c + k;
#pragma unroll
    for (int s = 0; s < N_SAMP; ++s) {
      uint32_t x0 = 0u, x1 = base_c + (uint32_t)s * 8192u;
      tf2x32(k0, k1, x0, x1);
      uint32_t bits = x0 ^ x1;
      bool cand = (bits >= th[s]);
      if (__any(cand)) {
        float u = __uint_as_float(0x3f800000u | (bits >> 9)) - 1.0f;
        u = fmaxf(u, tiny);
        float wv = -logf(u) * Ek;
        unsigned long long p = cand
            ? (((unsigned long long)__float_as_uint(wv) << 32) | k)
            : 0xFFFFFFFFFFFFFFFFULL;
#pragma unroll
        for (int off = 1; off < 64; off <<= 1) {
          unsigned long long op = shfl_xor_u64(p, off);
          p = (op < p) ? op : p;
        }
        if (p < champ[s]) {
          champ[s] = p;
          float wmin = __uint_as_float((uint32_t)(p >> 32));
          float ut = expf(-wmin) * 0.999999f;
          th[s] = ((uint32_t)(ut * 8388608.0f)) << 9;
        }
      }
    }
    Ek = Ekn;
  }
#pragma unroll
  for (int s = 0; s < N_SAMP; ++s) {
    if (lane == 0) {
      float v = __uint_as_float((uint32_t)(champ[s] >> 32));
      int id = (int)(uint32_t)(champ[s] & 0xFFFFFFFFu);
      size_t p = (size_t)row * N_SAMP + s;
      if (v < rmin[p]) { rmin[p] = v; ridx[p] = id; }
    }
  }
}

// ---------------- gather + mean + straight-through (u64 champion version) ----------------
__global__ __launch_bounds__(256) void gather_kernel(const float* __restrict__ emb,
                                                     const unsigned long long* __restrict__ champ,
                                                     const float* __restrict__ x,
                                                     float* __restrict__ outq,
                                                     float* __restrict__ outs) {
  int lane = threadIdx.x & 63;
  int row = (int)((blockIdx.x * blockDim.x + threadIdx.x) >> 6);
  int idx[N_SAMP];
#pragma unroll
  for (int s = 0; s < N_SAMP; ++s)
    idx[s] = (int)(uint32_t)(champ[(size_t)row * N_SAMP + s] & 0xFFFFFFFFu);
  if (lane < N_SAMP) outs[row * N_SAMP + lane] = (float)idx[lane];
#pragma unroll
  for (int h = 0; h < 2; ++h) {
    int c = h * 256 + lane * 4;
    float4 sum = make_float4(0.f, 0.f, 0.f, 0.f);
#pragma unroll
    for (int s = 0; s < N_SAMP; ++s) {
      float4 e = *(const float4*)(emb + (size_t)idx[s] * N_DIM + c);
      sum.x += e.x; sum.y += e.y; sum.z += e.z; sum.w += e.w;
    }
    float4 xv = *(const float4*)(x + (size_t)row * N_DIM + c);
    float4 o;
    o.x = xv.x + (sum.x / 10.0f - xv.x);
    o.y = xv.y + (sum.y / 10.0f - xv.y);
    o.z = xv.z + (sum.z / 10.0f - xv.z);
    o.w = xv.w + (sum.w / 10.0f - xv.w);
    *(float4*)(outq + (size_t)row * N_DIM + c) = o;
  }
}

// ---------------- fallback gather (int ridx version) ----------------
__global__ __launch_bounds__(256) void gather_fb_kernel(const float* __restrict__ emb,
                                                        const int* __restrict__ ridx,
                                                        const float* __restrict__ x,
                                                        float* __restrict__ outq,
                                                        float* __restrict__ outs) {
  int lane = threadIdx.x & 63;
  int row = (int)((blockIdx.x * blockDim.x + threadIdx.x) >> 6);
  int idx[N_SAMP];
#pragma unroll
  for (int s = 0; s < N_SAMP; ++s) idx[s] = ridx[row * N_SAMP + s];
  if (lane < N_SAMP) outs[row * N_SAMP + lane] = (float)idx[lane];
#pragma unroll
  for (int h = 0; h < 2; ++h) {
    int c = h * 256 + lane * 4;
    float4 sum = make_float4(0.f, 0.f, 0.f, 0.f);
#pragma unroll
    for (int s = 0; s < N_SAMP; ++s) {
      float4 e = *(const float4*)(emb + (size_t)idx[s] * N_DIM + c);
      sum.x += e.x; sum.y += e.y; sum.z += e.z; sum.w += e.w;
    }
    float4 xv = *(const float4*)(x + (size_t)row * N_DIM + c);
    float4 o;
    o.x = xv.x + (sum.x / 10.0f - xv.x);
    o.y = xv.y + (sum.y / 10.0f - xv.y);
    o.z = xv.z + (sum.z / 10.0f - xv.z);
    o.w = xv.w + (sum.w / 10.0f - xv.w);
    *(float4*)(outq + (size_t)row * N_DIM + c) = o;
  }
}

extern "C" void kernel_launch(void* const* d_in, const int* in_sizes, int n_in,
                              void* d_out, int out_size, void* d_ws, size_t ws_size,
                              hipStream_t stream) {
  const float* x = (const float*)d_in[0];
  const float* emb = (const float*)d_in[1];
  float* out_q = (float*)d_out;
  float* out_s = out_q + (size_t)N_ROWS * N_DIM;

  const size_t split_u = (size_t)N_ROWS * GK;  // ushorts per split buffer
  const size_t fixed_f = (size_t)N_ROWS + N_TOK + 2 * (size_t)N_ROWS * N_SAMP;
  const size_t out_f = (size_t)N_ROWS * N_DIM + (size_t)N_ROWS * N_SAMP;

  uint32_t s0 = 0u, s1 = 1u;   // skey = fold_in(key(0), 1)
  tf2x32(0u, 0u, s0, s1);

  // ---- preferred path: fused bf16x2 MFMA GEMM + sampler (no E materialization) ----
  {
    size_t need = (size_t)(N_ROWS + N_TOK) * 4            // xx, ee
                + (size_t)N_ROWS * N_SAMP * 8             // champ u64
                + 2 * split_u * 2;                        // A2, B2
    if (need <= ws_size) {
      float* xx = (float*)d_ws;
      float* ee = xx + N_ROWS;
      unsigned long long* champ = (unsigned long long*)(ee + N_TOK);
      unsigned short* A2 = (unsigned short*)(champ + (size_t)N_ROWS * N_SAMP);
      unsigned short* B2 = A2 + split_u;

      rownorm_kernel<<<2048, 256, 0, stream>>>(x, xx);
      rownorm_kernel<<<2048, 256, 0, stream>>>(emb, ee);
      init_champ_kernel<<<(N_ROWS * N_SAMP + 255) / 256, 256, 0, stream>>>(champ);
      split_kernel<<<N_ROWS * 128 / 256, 256, 0, stream>>>(x, A2, 0);
      split_kernel<<<N_ROWS * 128 / 256, 256, 0, stream>>>(emb, B2, 1);
      fused_gemm_sample_kernel<<<dim3(64, 64), 256, 0, stream>>>(
          A2, B2, xx, ee, champ, s0, s1);
      gather_kernel<<<2048, 256, 0, stream>>>(emb, champ, x, out_q, out_s);
      return;
    }
  }

  // ---- fallback: fp32 path with adaptive placement (r6-proven) ----
  float *xx, *ee, *rmin, *E;
  int* ridx;
  int KC = 0;
  for (int c = 8192; c >= 64; c >>= 1) {
    if ((fixed_f + (size_t)N_ROWS * c) * 4 <= ws_size) { KC = c; break; }
  }
  if (KC) {
    xx = (float*)d_ws;
    ee = xx + N_ROWS;
    rmin = ee + N_TOK;
    ridx = (int*)(rmin + (size_t)N_ROWS * N_SAMP);
    E = (float*)(ridx + (size_t)N_ROWS * N_SAMP);
  } else if (fixed_f * 4 <= ws_size) {
    KC = 512;
    xx = (float*)d_ws;
    ee = xx + N_ROWS;
    rmin = ee + N_TOK;
    ridx = (int*)(rmin + (size_t)N_ROWS * N_SAMP);
    E = out_q;
  } else {
    KC = 256;
    E = out_q;
    float* tail = out_q + (out_f - fixed_f);
    xx = tail;
    ee = xx + N_ROWS;
    rmin = ee + N_TOK;
    ridx = (int*)(rmin + (size_t)N_ROWS * N_SAMP);
  }

  rownorm_kernel<<<2048, 256, 0, stream>>>(x, xx);
  rownorm_kernel<<<2048, 256, 0, stream>>>(emb, ee);
  init_state_kernel<<<(N_ROWS * N_SAMP + 255) / 256, 256, 0, stream>>>(rmin, ridx);
  for (int ks = 0; ks < N_TOK; ks += KC) {
    gemm_nt_kernel<<<dim3(KC / 64, N_ROWS / 64), 256, 0, stream>>>(x, emb, xx, ee, E, ks, KC);
    sample_kernel<<<2048, 256, 0, stream>>>(E, rmin, ridx, ks, KC, s0, s1);
  }
  gather_fb_kernel<<<2048, 256, 0, stream>>>(emb, ridx, x, out_q, out_s);
}

// Round 9
// 1749.853 us; speedup vs baseline: 1.4627x; 1.4627x over previous
//
#include <hip/hip_runtime.h>
#include <stdint.h>
#include <math.h>

#define N_ROWS 8192
#define N_TOK  8192
#define N_DIM  512
#define N_SAMP 10
#define GK     1536   // 3 * 512, bf16x2 split zones

typedef __attribute__((ext_vector_type(8))) short bf16x8_t;
typedef __attribute__((ext_vector_type(4))) float f32x4_t;

// ---------------- JAX threefry2x32 (exact; rotl forced to 1-op alignbit) ----------------
__host__ __device__ __forceinline__ void tf2x32(uint32_t ks0, uint32_t ks1,
                                                uint32_t& x0, uint32_t& x1) {
  uint32_t ks2 = ks0 ^ ks1 ^ 0x1BD11BDAu;
  x0 += ks0; x1 += ks1;
#define TF_ROUND(r) { x0 += x1; x1 = __builtin_rotateleft32(x1, r); x1 ^= x0; }
  TF_ROUND(13) TF_ROUND(15) TF_ROUND(26) TF_ROUND(6)
  x0 += ks1; x1 += ks2 + 1u;
  TF_ROUND(17) TF_ROUND(29) TF_ROUND(16) TF_ROUND(24)
  x0 += ks2; x1 += ks0 + 2u;
  TF_ROUND(13) TF_ROUND(15) TF_ROUND(26) TF_ROUND(6)
  x0 += ks0; x1 += ks1 + 3u;
  TF_ROUND(17) TF_ROUND(29) TF_ROUND(16) TF_ROUND(24)
  x0 += ks1; x1 += ks2 + 4u;
  TF_ROUND(13) TF_ROUND(15) TF_ROUND(26) TF_ROUND(6)
  x0 += ks2; x1 += ks0 + 5u;
#undef TF_ROUND
}

__device__ __forceinline__ unsigned short f2bf_rne(float f) {
  uint32_t u = __float_as_uint(f);
  uint32_t r = (u + 0x7fffu + ((u >> 16) & 1u)) >> 16;
  return (unsigned short)r;
}
__device__ __forceinline__ float bf2f(unsigned short h) {
  return __uint_as_float((uint32_t)h << 16);
}

__device__ __forceinline__ unsigned long long shfl_xor_u64(unsigned long long v, int off) {
  uint32_t lo = (uint32_t)v, hi = (uint32_t)(v >> 32);
  lo = (uint32_t)__shfl_xor((int)lo, off, 64);
  hi = (uint32_t)__shfl_xor((int)hi, off, 64);
  return ((unsigned long long)hi << 32) | lo;
}

// ---------------- row sum-of-squares ----------------
__global__ __launch_bounds__(256) void rownorm_kernel(const float* __restrict__ M,
                                                      float* __restrict__ out) {
  int lane = threadIdx.x & 63;
  int row = (int)((blockIdx.x * blockDim.x + threadIdx.x) >> 6);
  const float* p = M + (size_t)row * N_DIM;
  float acc = 0.f;
#pragma unroll
  for (int d = 0; d < N_DIM; d += 64) {
    float v = p[d + lane];
    acc = fmaf(v, v, acc);
  }
#pragma unroll
  for (int off = 32; off; off >>= 1) acc += __shfl_xor(acc, off, 64);
  if (lane == 0) out[row] = acc;
}

// ---------------- state init ----------------
__global__ __launch_bounds__(256) void init_champ_kernel(unsigned long long* __restrict__ c) {
  int i = blockIdx.x * 256 + threadIdx.x;
  if (i < N_ROWS * N_SAMP) c[i] = 0xFFFFFFFFFFFFFFFFULL;
}

__global__ __launch_bounds__(256) void init_state_kernel(float* __restrict__ rmin,
                                                         int* __restrict__ ridx) {
  int i = blockIdx.x * 256 + threadIdx.x;
  if (i < N_ROWS * N_SAMP) { rmin[i] = INFINITY; ridx[i] = 0; }
}

// ---------------- bf16x2 split ----------------
__global__ __launch_bounds__(256) void split_kernel(const float* __restrict__ src,
                                                    unsigned short* __restrict__ dst,
                                                    int mode) {
  int t = blockIdx.x * 256 + threadIdx.x;
  int row = t >> 7;
  int c = (t & 127) << 2;
  float4 v = *(const float4*)(src + (size_t)row * N_DIM + c);
  ushort4 hi, lo;
  hi.x = f2bf_rne(v.x); lo.x = f2bf_rne(v.x - bf2f(hi.x));
  hi.y = f2bf_rne(v.y); lo.y = f2bf_rne(v.y - bf2f(hi.y));
  hi.z = f2bf_rne(v.z); lo.z = f2bf_rne(v.z - bf2f(hi.z));
  hi.w = f2bf_rne(v.w); lo.w = f2bf_rne(v.w - bf2f(hi.w));
  unsigned short* base = dst + (size_t)row * GK;
  *(ushort4*)(base + c) = hi;
  if (mode == 0) {
    *(ushort4*)(base + 512 + c) = lo;
    *(ushort4*)(base + 1024 + c) = hi;
  } else {
    *(ushort4*)(base + 512 + c) = hi;
    *(ushort4*)(base + 1024 + c) = lo;
  }
}

__device__ __forceinline__ void async_cp16(const void* g, void* l) {
  __builtin_amdgcn_global_load_lds((const __attribute__((address_space(1))) void*)g,
                                   (__attribute__((address_space(3))) void*)l, 16, 0, 0);
}

// ---------------- FUSED bf16 MFMA GEMM + serial-style multinomial sampler ----------------
// v9 = v3 structure (best: 1528 us total) with the always-predicated accept
// body MINIMIZED (4 failed rounds prove the compiler if-converts it on every
// eval regardless of branch phrasing; so shrink what gets issued):
//  - negEk hoisted per kk; wv = logf(u)*negEk  (bit-identical to -logf(u)*Ek)
//  - threshold update WITHOUT expf: (1-wv) <= e^-wv always, so
//    T = (uint)max((1-wv)*8388599, 0) << 9 is strictly conservative
//    (8388599 = 2^23 * 0.99999893 absorbs subtract/mul rounding; margin
//    wv^2/2 >= float error for all wv). Screens only ever looser -> exact.
//  - same cheap bound in the snapshot conversion.
// wv computation, u64 packing/ordering, atomicMin publication unchanged ->
// identical picks, identical output.
__global__ __launch_bounds__(256) void fused_gemm_sample_kernel(
    const unsigned short* __restrict__ A2, const unsigned short* __restrict__ B2,
    const float* __restrict__ xx, const float* __restrict__ ee,
    unsigned long long* __restrict__ champ, uint32_t k0, uint32_t k1) {
  __shared__ __align__(16) unsigned char smem[65536];
  unsigned short* As = (unsigned short*)smem;              // 128*64 ushort = 16 KB
  unsigned short* Bs = (unsigned short*)(smem + 16384);    // 16 KB
  float* Et = (float*)smem;                                // 128*128 f32 = 64 KB (reuse)
  int tid = threadIdx.x;
  int w = tid >> 6, l = tid & 63;

  int bid = blockIdx.y * gridDim.x + blockIdx.x;
  int by = bid & 63;   // row-block: fast -> spreads rows across XCDs
  int bx = bid >> 6;   // col-block: slow -> generations, screens tighten

  int row0 = by * 128;
  int col0 = bx * 128;
  int wm = (w & 1) * 64, wn = (w >> 1) * 64;
  int quad = l >> 4, r15 = l & 15;

  f32x4_t acc[4][4];
#pragma unroll
  for (int i = 0; i < 4; ++i)
#pragma unroll
    for (int j = 0; j < 4; ++j) acc[i][j] = (f32x4_t){0.f, 0.f, 0.f, 0.f};

  int srow[4], skc[4];
#pragma unroll
  for (int r = 0; r < 4; ++r) {
    int c = tid + 256 * r;
    srow[r] = c >> 3;
    skc[r] = (c & 7) ^ (srow[r] & 7);
  }

  for (int kt = 0; kt < GK; kt += 64) {
#pragma unroll
    for (int r = 0; r < 4; ++r) {
      int c = tid + 256 * r;
      async_cp16(A2 + (size_t)(row0 + srow[r]) * GK + kt + skc[r] * 8, As + c * 8);
      async_cp16(B2 + (size_t)(col0 + srow[r]) * GK + kt + skc[r] * 8, Bs + c * 8);
    }
    __syncthreads();

#pragma unroll
    for (int kk2 = 0; kk2 < 2; ++kk2) {
      bf16x8_t af[4], bf[4];
#pragma unroll
      for (int i = 0; i < 4; ++i) {
        int row = wm + i * 16 + r15;
        int qc = (kk2 * 4 + quad) ^ (r15 & 7);
        af[i] = *(const bf16x8_t*)&As[row * 64 + qc * 8];
      }
#pragma unroll
      for (int j = 0; j < 4; ++j) {
        int row = wn + j * 16 + r15;
        int qc = (kk2 * 4 + quad) ^ (r15 & 7);
        bf[j] = *(const bf16x8_t*)&Bs[row * 64 + qc * 8];
      }
#pragma unroll
      for (int i = 0; i < 4; ++i)
#pragma unroll
        for (int j = 0; j < 4; ++j)
          acc[i][j] = __builtin_amdgcn_mfma_f32_16x16x32_bf16(af[i], bf[j], acc[i][j], 0, 0, 0);
    }
    __syncthreads();
  }

  // ---- (1) write Ek tile to LDS (exp hoisted: exactly once per element) ----
  const float inv_nt = 1.f / 8192.f;
  float eev[4];
#pragma unroll
  for (int j = 0; j < 4; ++j) eev[j] = ee[col0 + wn + j * 16 + r15];
#pragma unroll
  for (int i = 0; i < 4; ++i) {
#pragma unroll
    for (int r = 0; r < 4; ++r) {
      int lrow = wm + i * 16 + quad * 4 + r;
      float xxv = xx[row0 + lrow];
      int mxr = lrow & 31;
#pragma unroll
      for (int j = 0; j < 4; ++j) {
        int col = wn + j * 16 + r15;
        float dist = (xxv + eev[j] - 2.0f * acc[i][j][r]) * inv_nt;
        Et[lrow * 128 + (col ^ mxr)] = expf(dist);   // bit-identical to r6 E value
      }
    }
  }
  __syncthreads();

  // ---- (2) serial scan: thread = (row, column-half); minimized body ----
  int lrow = tid >> 1, half = tid & 1;
  int grow = row0 + lrow;
  unsigned long long* cg = champ + (size_t)grow * N_SAMP;
  unsigned long long cw[N_SAMP];
  uint32_t th[N_SAMP];
  const float TCONV = 8388599.0f;          // 2^23 * 0.99999893 (rounding guard)
#pragma unroll
  for (int s = 0; s < N_SAMP; ++s) {
    unsigned long long c = cg[s];          // snapshot: stale/torn only -> looser screen
    cw[s] = 0xFFFFFFFFFFFFFFFFULL;         // local champion independent of snapshot
    uint32_t hi = (uint32_t)(c >> 32);
    uint32_t t = 0u;
    if (hi < 0x7F800000u) {
      float wvc = __uint_as_float(hi);
      float tf = fmaxf((1.0f - wvc) * TCONV, 0.0f);  // (1-x) <= e^-x: conservative
      t = ((uint32_t)tf) << 9;
    }
    th[s] = t;
  }
  const float tiny = 1.1754943508222875e-38f;
  uint32_t row_c = (uint32_t)grow * 81920u;
  const float* Erow = Et + lrow * 128 + half * 64;
  int mxr = lrow & 31;
  uint32_t kbase = (uint32_t)(col0 + half * 64);

  for (int kk = 0; kk < 64; ++kk) {
    float negEk = -Erow[kk ^ mxr];         // hoisted per kk; 2-way bank alias = free
    uint32_t kglob = kbase + (uint32_t)kk;
    uint32_t base_c = row_c + kglob;
#pragma unroll
    for (int s = 0; s < N_SAMP; ++s) {
      uint32_t x0 = 0u, x1 = base_c + (uint32_t)s * 8192u;
      tf2x32(k0, k1, x0, x1);
      uint32_t bits = x0 ^ x1;
      bool cand = (bits >= th[s]);
      float u = fmaxf(__uint_as_float(0x3f800000u | (bits >> 9)) - 1.0f, tiny);
      float wv = logf(u) * negEk;          // == -logf(u)*Ek bit-exactly
      unsigned long long p = cand
          ? (((unsigned long long)__float_as_uint(wv) << 32) | kglob)
          : 0xFFFFFFFFFFFFFFFFULL;
      if (p < cw[s]) {
        cw[s] = p;
        float tf = fmaxf((1.0f - wv) * TCONV, 0.0f);   // cheap conservative screen
        uint32_t nt = ((uint32_t)tf) << 9;
        th[s] = (nt > th[s]) ? nt : th[s]; // never loosen below snapshot screen
      }
    }
  }
#pragma unroll
  for (int s = 0; s < N_SAMP; ++s)
    if (cw[s] != 0xFFFFFFFFFFFFFFFFULL) atomicMin(&cg[s], cw[s]);
}

// ---------------- fp32 NT GEMM (fallback, r6-proven) with E-epilogue ----------------
__global__ __launch_bounds__(256) void gemm_nt_kernel(const float* __restrict__ A,
                                                      const float* __restrict__ B,
                                                      const float* __restrict__ xx,
                                                      const float* __restrict__ ee,
                                                      float* __restrict__ E,
                                                      int ks, int KC) {
  __shared__ __align__(16) float Asf[32][68];
  __shared__ __align__(16) float Bsf[32][68];
  int tid = threadIdx.x;
  int row0 = blockIdx.y * 64;
  int colB0 = blockIdx.x * 64 + ks;
  int tx = tid & 15, ty = tid >> 4;
  float acc[4][4] = {};
  for (int d0 = 0; d0 < N_DIM; d0 += 32) {
#pragma unroll
    for (int r = 0; r < 2; ++r) {
      int c = tid + 256 * r;
      int m = c >> 3;
      int dv = (c & 7) << 2;
      const float4 va = *(const float4*)(A + (size_t)(row0 + m) * N_DIM + d0 + dv);
      Asf[dv + 0][m] = va.x; Asf[dv + 1][m] = va.y;
      Asf[dv + 2][m] = va.z; Asf[dv + 3][m] = va.w;
      const float4 vb = *(const float4*)(B + (size_t)(colB0 + m) * N_DIM + d0 + dv);
      Bsf[dv + 0][m] = vb.x; Bsf[dv + 1][m] = vb.y;
      Bsf[dv + 2][m] = vb.z; Bsf[dv + 3][m] = vb.w;
    }
    __syncthreads();
#pragma unroll
    for (int dd = 0; dd < 32; ++dd) {
      float4 a4 = *(const float4*)&Asf[dd][ty << 2];
      float4 b4 = *(const float4*)&Bsf[dd][tx << 2];
      float av[4] = {a4.x, a4.y, a4.z, a4.w};
      float bv[4] = {b4.x, b4.y, b4.z, b4.w};
#pragma unroll
      for (int i = 0; i < 4; ++i)
#pragma unroll
        for (int j = 0; j < 4; ++j)
          acc[i][j] = fmaf(av[i], bv[j], acc[i][j]);
    }
    __syncthreads();
  }
  const float inv_nt = 1.f / 8192.f;
  int colC0 = blockIdx.x * 64;
  float eev[4];
#pragma unroll
  for (int j = 0; j < 4; ++j) eev[j] = ee[ks + colC0 + (tx << 2) + j];
#pragma unroll
  for (int i = 0; i < 4; ++i) {
    int grow = row0 + (ty << 2) + i;
    float xxv = xx[grow];
    float4 v;
    v.x = expf((xxv + eev[0] - 2.0f * acc[i][0]) * inv_nt);
    v.y = expf((xxv + eev[1] - 2.0f * acc[i][1]) * inv_nt);
    v.z = expf((xxv + eev[2] - 2.0f * acc[i][2]) * inv_nt);
    v.w = expf((xxv + eev[3] - 2.0f * acc[i][3]) * inv_nt);
    *(float4*)(E + (size_t)grow * KC + colC0 + (tx << 2)) = v;
  }
}

// ---------------- fallback sampler: wave-shared champion + bits screen ----------------
__global__ __launch_bounds__(256) void sample_kernel(const float* __restrict__ E,
                                                     float* __restrict__ rmin,
                                                     int* __restrict__ ridx,
                                                     int ks, int KC,
                                                     uint32_t k0, uint32_t k1) {
  int lane = threadIdx.x & 63;
  int row = (int)((blockIdx.x * blockDim.x + threadIdx.x) >> 6);
  unsigned long long champ[N_SAMP];
  uint32_t th[N_SAMP];
#pragma unroll
  for (int s = 0; s < N_SAMP; ++s) { champ[s] = 0xFFFFFFFFFFFFFFFFULL; th[s] = 0u; }
  const float tiny = 1.1754943508222875e-38f;
  uint32_t row_c = (uint32_t)row * 81920u;
  const float* Erow = E + (size_t)row * KC;

  float Ek = Erow[lane];
  for (int kk = lane; kk < KC; kk += 64) {
    int nk = (kk + 64 < KC) ? kk + 64 : kk;
    float Ekn = Erow[nk];
    uint32_t k = (uint32_t)(ks + kk);
    uint32_t base_c = row_c + k;
#pragma unroll
    for (int s = 0; s < N_SAMP; ++s) {
      uint32_t x0 = 0u, x1 = base_c + (uint32_t)s * 8192u;
      tf2x32(k0, k1, x0, x1);
      uint32_t bits = x0 ^ x1;
      bool cand = (bits >= th[s]);
      if (__any(cand)) {
        float u = __uint_as_float(0x3f800000u | (bits >> 9)) - 1.0f;
        u = fmaxf(u, tiny);
        float wv = -logf(u) * Ek;
        unsigned long long p = cand
            ? (((unsigned long long)__float_as_uint(wv) << 32) | k)
            : 0xFFFFFFFFFFFFFFFFULL;
#pragma unroll
        for (int off = 1; off < 64; off <<= 1) {
          unsigned long long op = shfl_xor_u64(p, off);
          p = (op < p) ? op : p;
        }
        if (p < champ[s]) {
          champ[s] = p;
          float wmin = __uint_as_float((uint32_t)(p >> 32));
          float ut = expf(-wmin) * 0.999999f;
          th[s] = ((uint32_t)(ut * 8388608.0f)) << 9;
        }
      }
    }
    Ek = Ekn;
  }
#pragma unroll
  for (int s = 0; s < N_SAMP; ++s) {
    if (lane == 0) {
      float v = __uint_as_float((uint32_t)(champ[s] >> 32));
      int id = (int)(uint32_t)(champ[s] & 0xFFFFFFFFu);
      size_t p = (size_t)row * N_SAMP + s;
      if (v < rmin[p]) { rmin[p] = v; ridx[p] = id; }
    }
  }
}

// ---------------- gather + mean + straight-through (u64 champion version) ----------------
__global__ __launch_bounds__(256) void gather_kernel(const float* __restrict__ emb,
                                                     const unsigned long long* __restrict__ champ,
                                                     const float* __restrict__ x,
                                                     float* __restrict__ outq,
                                                     float* __restrict__ outs) {
  int lane = threadIdx.x & 63;
  int row = (int)((blockIdx.x * blockDim.x + threadIdx.x) >> 6);
  int idx[N_SAMP];
#pragma unroll
  for (int s = 0; s < N_SAMP; ++s)
    idx[s] = (int)(uint32_t)(champ[(size_t)row * N_SAMP + s] & 0xFFFFFFFFu);
  if (lane < N_SAMP) outs[row * N_SAMP + lane] = (float)idx[lane];
#pragma unroll
  for (int h = 0; h < 2; ++h) {
    int c = h * 256 + lane * 4;
    float4 sum = make_float4(0.f, 0.f, 0.f, 0.f);
#pragma unroll
    for (int s = 0; s < N_SAMP; ++s) {
      float4 e = *(const float4*)(emb + (size_t)idx[s] * N_DIM + c);
      sum.x += e.x; sum.y += e.y; sum.z += e.z; sum.w += e.w;
    }
    float4 xv = *(const float4*)(x + (size_t)row * N_DIM + c);
    float4 o;
    o.x = xv.x + (sum.x / 10.0f - xv.x);
    o.y = xv.y + (sum.y / 10.0f - xv.y);
    o.z = xv.z + (sum.z / 10.0f - xv.z);
    o.w = xv.w + (sum.w / 10.0f - xv.w);
    *(float4*)(outq + (size_t)row * N_DIM + c) = o;
  }
}

// ---------------- fallback gather (int ridx version) ----------------
__global__ __launch_bounds__(256) void gather_fb_kernel(const float* __restrict__ emb,
                                                        const int* __restrict__ ridx,
                                                        const float* __restrict__ x,
                                                        float* __restrict__ outq,
                                                        float* __restrict__ outs) {
  int lane = threadIdx.x & 63;
  int row = (int)((blockIdx.x * blockDim.x + threadIdx.x) >> 6);
  int idx[N_SAMP];
#pragma unroll
  for (int s = 0; s < N_SAMP; ++s) idx[s] = ridx[row * N_SAMP + s];
  if (lane < N_SAMP) outs[row * N_SAMP + lane] = (float)idx[lane];
#pragma unroll
  for (int h = 0; h < 2; ++h) {
    int c = h * 256 + lane * 4;
    float4 sum = make_float4(0.f, 0.f, 0.f, 0.f);
#pragma unroll
    for (int s = 0; s < N_SAMP; ++s) {
      float4 e = *(const float4*)(emb + (size_t)idx[s] * N_DIM + c);
      sum.x += e.x; sum.y += e.y; sum.z += e.z; sum.w += e.w;
    }
    float4 xv = *(const float4*)(x + (size_t)row * N_DIM + c);
    float4 o;
    o.x = xv.x + (sum.x / 10.0f - xv.x);
    o.y = xv.y + (sum.y / 10.0f - xv.y);
    o.z = xv.z + (sum.z / 10.0f - xv.z);
    o.w = xv.w + (sum.w / 10.0f - xv.w);
    *(float4*)(outq + (size_t)row * N_DIM + c) = o;
  }
}

extern "C" void kernel_launch(void* const* d_in, const int* in_sizes, int n_in,
                              void* d_out, int out_size, void* d_ws, size_t ws_size,
                              hipStream_t stream) {
  const float* x = (const float*)d_in[0];
  const float* emb = (const float*)d_in[1];
  float* out_q = (float*)d_out;
  float* out_s = out_q + (size_t)N_ROWS * N_DIM;

  const size_t split_u = (size_t)N_ROWS * GK;  // ushorts per split buffer
  const size_t fixed_f = (size_t)N_ROWS + N_TOK + 2 * (size_t)N_ROWS * N_SAMP;
  const size_t out_f = (size_t)N_ROWS * N_DIM + (size_t)N_ROWS * N_SAMP;

  uint32_t s0 = 0u, s1 = 1u;   // skey = fold_in(key(0), 1)
  tf2x32(0u, 0u, s0, s1);

  // ---- preferred path: fused bf16x2 MFMA GEMM + sampler (no E materialization) ----
  {
    size_t need = (size_t)(N_ROWS + N_TOK) * 4            // xx, ee
                + (size_t)N_ROWS * N_SAMP * 8             // champ u64
                + 2 * split_u * 2;                        // A2, B2
    if (need <= ws_size) {
      float* xx = (float*)d_ws;
      float* ee = xx + N_ROWS;
      unsigned long long* champ = (unsigned long long*)(ee + N_TOK);
      unsigned short* A2 = (unsigned short*)(champ + (size_t)N_ROWS * N_SAMP);
      unsigned short* B2 = A2 + split_u;

      rownorm_kernel<<<2048, 256, 0, stream>>>(x, xx);
      rownorm_kernel<<<2048, 256, 0, stream>>>(emb, ee);
      init_champ_kernel<<<(N_ROWS * N_SAMP + 255) / 256, 256, 0, stream>>>(champ);
      split_kernel<<<N_ROWS * 128 / 256, 256, 0, stream>>>(x, A2, 0);
      split_kernel<<<N_ROWS * 128 / 256, 256, 0, stream>>>(emb, B2, 1);
      fused_gemm_sample_kernel<<<dim3(64, 64), 256, 0, stream>>>(
          A2, B2, xx, ee, champ, s0, s1);
      gather_kernel<<<2048, 256, 0, stream>>>(emb, champ, x, out_q, out_s);
      return;
    }
  }

  // ---- fallback: fp32 path with adaptive placement (r6-proven) ----
  float *xx, *ee, *rmin, *E;
  int* ridx;
  int KC = 0;
  for (int c = 8192; c >= 64; c >>= 1) {
    if ((fixed_f + (size_t)N_ROWS * c) * 4 <= ws_size) { KC = c; break; }
  }
  if (KC) {
    xx = (float*)d_ws;
    ee = xx + N_ROWS;
    rmin = ee + N_TOK;
    ridx = (int*)(rmin + (size_t)N_ROWS * N_SAMP);
    E = (float*)(ridx + (size_t)N_ROWS * N_SAMP);
  } else if (fixed_f * 4 <= ws_size) {
    KC = 512;
    xx = (float*)d_ws;
    ee = xx + N_ROWS;
    rmin = ee + N_TOK;
    ridx = (int*)(rmin + (size_t)N_ROWS * N_SAMP);
    E = out_q;
  } else {
    KC = 256;
    E = out_q;
    float* tail = out_q + (out_f - fixed_f);
    xx = tail;
    ee = xx + N_ROWS;
    rmin = ee + N_TOK;
    ridx = (int*)(rmin + (size_t)N_ROWS * N_SAMP);
  }

  rownorm_kernel<<<2048, 256, 0, stream>>>(x, xx);
  rownorm_kernel<<<2048, 256, 0, stream>>>(emb, ee);
  init_state_kernel<<<(N_ROWS * N_SAMP + 255) / 256, 256, 0, stream>>>(rmin, ridx);
  for (int ks = 0; ks < N_TOK; ks += KC) {
    gemm_nt_kernel<<<dim3(KC / 64, N_ROWS / 64), 256, 0, stream>>>(x, emb, xx, ee, E, ks, KC);
    sample_kernel<<<2048, 256, 0, stream>>>(E, rmin, ridx, ks, KC, s0, s1);
  }
  gather_fb_kernel<<<2048, 256, 0, stream>>>(emb, ridx, x, out_q, out_s);
}

// Round 10
// 1523.499 us; speedup vs baseline: 1.6801x; 1.1486x over previous
//
#include <hip/hip_runtime.h>
#include <stdint.h>
#include <math.h>

#define N_ROWS 8192
#define N_TOK  8192
#define N_DIM  512
#define N_SAMP 10
#define GK     1536   // 3 * 512, bf16x2 split zones

typedef __attribute__((ext_vector_type(8))) short bf16x8_t;
typedef __attribute__((ext_vector_type(4))) float f32x4_t;

// ---------------- JAX threefry2x32 (exact; rotl forced to 1-op alignbit) ----------------
__host__ __device__ __forceinline__ void tf2x32(uint32_t ks0, uint32_t ks1,
                                                uint32_t& x0, uint32_t& x1) {
  uint32_t ks2 = ks0 ^ ks1 ^ 0x1BD11BDAu;
  x0 += ks0; x1 += ks1;
#define TF_ROUND(r) { x0 += x1; x1 = __builtin_rotateleft32(x1, r); x1 ^= x0; }
  TF_ROUND(13) TF_ROUND(15) TF_ROUND(26) TF_ROUND(6)
  x0 += ks1; x1 += ks2 + 1u;
  TF_ROUND(17) TF_ROUND(29) TF_ROUND(16) TF_ROUND(24)
  x0 += ks2; x1 += ks0 + 2u;
  TF_ROUND(13) TF_ROUND(15) TF_ROUND(26) TF_ROUND(6)
  x0 += ks0; x1 += ks1 + 3u;
  TF_ROUND(17) TF_ROUND(29) TF_ROUND(16) TF_ROUND(24)
  x0 += ks1; x1 += ks2 + 4u;
  TF_ROUND(13) TF_ROUND(15) TF_ROUND(26) TF_ROUND(6)
  x0 += ks2; x1 += ks0 + 5u;
#undef TF_ROUND
}

__device__ __forceinline__ unsigned short f2bf_rne(float f) {
  uint32_t u = __float_as_uint(f);
  uint32_t r = (u + 0x7fffu + ((u >> 16) & 1u)) >> 16;
  return (unsigned short)r;
}
__device__ __forceinline__ float bf2f(unsigned short h) {
  return __uint_as_float((uint32_t)h << 16);
}

__device__ __forceinline__ unsigned long long shfl_xor_u64(unsigned long long v, int off) {
  uint32_t lo = (uint32_t)v, hi = (uint32_t)(v >> 32);
  lo = (uint32_t)__shfl_xor((int)lo, off, 64);
  hi = (uint32_t)__shfl_xor((int)hi, off, 64);
  return ((unsigned long long)hi << 32) | lo;
}

// ---------------- row sum-of-squares ----------------
__global__ __launch_bounds__(256) void rownorm_kernel(const float* __restrict__ M,
                                                      float* __restrict__ out) {
  int lane = threadIdx.x & 63;
  int row = (int)((blockIdx.x * blockDim.x + threadIdx.x) >> 6);
  const float* p = M + (size_t)row * N_DIM;
  float acc = 0.f;
#pragma unroll
  for (int d = 0; d < N_DIM; d += 64) {
    float v = p[d + lane];
    acc = fmaf(v, v, acc);
  }
#pragma unroll
  for (int off = 32; off; off >>= 1) acc += __shfl_xor(acc, off, 64);
  if (lane == 0) out[row] = acc;
}

// ---------------- state init ----------------
__global__ __launch_bounds__(256) void init_champ_kernel(unsigned long long* __restrict__ c) {
  int i = blockIdx.x * 256 + threadIdx.x;
  if (i < N_ROWS * N_SAMP) c[i] = 0xFFFFFFFFFFFFFFFFULL;
}

__global__ __launch_bounds__(256) void init_state_kernel(float* __restrict__ rmin,
                                                         int* __restrict__ ridx) {
  int i = blockIdx.x * 256 + threadIdx.x;
  if (i < N_ROWS * N_SAMP) { rmin[i] = INFINITY; ridx[i] = 0; }
}

// ---------------- bf16x2 split ----------------
__global__ __launch_bounds__(256) void split_kernel(const float* __restrict__ src,
                                                    unsigned short* __restrict__ dst,
                                                    int mode) {
  int t = blockIdx.x * 256 + threadIdx.x;
  int row = t >> 7;
  int c = (t & 127) << 2;
  float4 v = *(const float4*)(src + (size_t)row * N_DIM + c);
  ushort4 hi, lo;
  hi.x = f2bf_rne(v.x); lo.x = f2bf_rne(v.x - bf2f(hi.x));
  hi.y = f2bf_rne(v.y); lo.y = f2bf_rne(v.y - bf2f(hi.y));
  hi.z = f2bf_rne(v.z); lo.z = f2bf_rne(v.z - bf2f(hi.z));
  hi.w = f2bf_rne(v.w); lo.w = f2bf_rne(v.w - bf2f(hi.w));
  unsigned short* base = dst + (size_t)row * GK;
  *(ushort4*)(base + c) = hi;
  if (mode == 0) {
    *(ushort4*)(base + 512 + c) = lo;
    *(ushort4*)(base + 1024 + c) = hi;
  } else {
    *(ushort4*)(base + 512 + c) = hi;
    *(ushort4*)(base + 1024 + c) = lo;
  }
}

__device__ __forceinline__ void async_cp16(const void* g, void* l) {
  __builtin_amdgcn_global_load_lds((const __attribute__((address_space(1))) void*)g,
                                   (__attribute__((address_space(3))) void*)l, 16, 0, 0);
}

// ---------------- FUSED bf16 MFMA GEMM + serial-style multinomial sampler ----------------
// Final form = round-3 kernel (session best: 1528 us E2E, measured).
// Block mapping by=bid&63 (fast), bx=bid>>6 (slow) => column-panels run as
// sequential GENERATIONS per row: later generations snapshot champions
// published by earlier ones -> tight bits-screen, accept body (real exec
// branch, ~never taken; verified by v9's +0.37G instr delta when hoisted)
// stays off the issue path. For fixed by, all col-blocks share an XCD under
// round-robin dispatch -> champion atomics + snapshots hit one L2, A-panels
// L2-resident (FETCH 250 MB vs 862 MB unswizzled).
// Scan hot loop: threefry(72 VALU) + xor + cmp, ~90% VALUBusy = issue-bound.
__global__ __launch_bounds__(256) void fused_gemm_sample_kernel(
    const unsigned short* __restrict__ A2, const unsigned short* __restrict__ B2,
    const float* __restrict__ xx, const float* __restrict__ ee,
    unsigned long long* __restrict__ champ, uint32_t k0, uint32_t k1) {
  __shared__ __align__(16) unsigned char smem[65536];
  unsigned short* As = (unsigned short*)smem;              // 128*64 ushort = 16 KB
  unsigned short* Bs = (unsigned short*)(smem + 16384);    // 16 KB
  float* Et = (float*)smem;                                // 128*128 f32 = 64 KB (reuse)
  int tid = threadIdx.x;
  int w = tid >> 6, l = tid & 63;

  int bid = blockIdx.y * gridDim.x + blockIdx.x;
  int by = bid & 63;   // row-block: fast -> spreads rows across XCDs
  int bx = bid >> 6;   // col-block: slow -> generations, screens tighten

  int row0 = by * 128;
  int col0 = bx * 128;
  int wm = (w & 1) * 64, wn = (w >> 1) * 64;
  int quad = l >> 4, r15 = l & 15;

  f32x4_t acc[4][4];
#pragma unroll
  for (int i = 0; i < 4; ++i)
#pragma unroll
    for (int j = 0; j < 4; ++j) acc[i][j] = (f32x4_t){0.f, 0.f, 0.f, 0.f};

  int srow[4], skc[4];
#pragma unroll
  for (int r = 0; r < 4; ++r) {
    int c = tid + 256 * r;
    srow[r] = c >> 3;
    skc[r] = (c & 7) ^ (srow[r] & 7);
  }

  for (int kt = 0; kt < GK; kt += 64) {
#pragma unroll
    for (int r = 0; r < 4; ++r) {
      int c = tid + 256 * r;
      async_cp16(A2 + (size_t)(row0 + srow[r]) * GK + kt + skc[r] * 8, As + c * 8);
      async_cp16(B2 + (size_t)(col0 + srow[r]) * GK + kt + skc[r] * 8, Bs + c * 8);
    }
    __syncthreads();

#pragma unroll
    for (int kk2 = 0; kk2 < 2; ++kk2) {
      bf16x8_t af[4], bf[4];
#pragma unroll
      for (int i = 0; i < 4; ++i) {
        int row = wm + i * 16 + r15;
        int qc = (kk2 * 4 + quad) ^ (r15 & 7);
        af[i] = *(const bf16x8_t*)&As[row * 64 + qc * 8];
      }
#pragma unroll
      for (int j = 0; j < 4; ++j) {
        int row = wn + j * 16 + r15;
        int qc = (kk2 * 4 + quad) ^ (r15 & 7);
        bf[j] = *(const bf16x8_t*)&Bs[row * 64 + qc * 8];
      }
#pragma unroll
      for (int i = 0; i < 4; ++i)
#pragma unroll
        for (int j = 0; j < 4; ++j)
          acc[i][j] = __builtin_amdgcn_mfma_f32_16x16x32_bf16(af[i], bf[j], acc[i][j], 0, 0, 0);
    }
    __syncthreads();
  }

  // ---- (1) write Ek tile to LDS (exp hoisted: exactly once per element) ----
  const float inv_nt = 1.f / 8192.f;
  float eev[4];
#pragma unroll
  for (int j = 0; j < 4; ++j) eev[j] = ee[col0 + wn + j * 16 + r15];
#pragma unroll
  for (int i = 0; i < 4; ++i) {
#pragma unroll
    for (int r = 0; r < 4; ++r) {
      int lrow = wm + i * 16 + quad * 4 + r;
      float xxv = xx[row0 + lrow];
      int mxr = lrow & 31;
#pragma unroll
      for (int j = 0; j < 4; ++j) {
        int col = wn + j * 16 + r15;
        float dist = (xxv + eev[j] - 2.0f * acc[i][j][r]) * inv_nt;
        Et[lrow * 128 + (col ^ mxr)] = expf(dist);   // bit-identical to r6 E value
      }
    }
  }
  __syncthreads();

  // ---- (2) serial scan: thread = (row, column-half) ----
  int lrow = tid >> 1, half = tid & 1;
  int grow = row0 + lrow;
  unsigned long long* cg = champ + (size_t)grow * N_SAMP;
  unsigned long long cw[N_SAMP];
  uint32_t th[N_SAMP];
  int improved = 0;
#pragma unroll
  for (int s = 0; s < N_SAMP; ++s) {
    unsigned long long c = cg[s];          // snapshot: stale/torn only -> looser screen
    cw[s] = 0xFFFFFFFFFFFFFFFFULL;         // local champion independent of snapshot
    uint32_t hi = (uint32_t)(c >> 32);
    uint32_t t = 0u;
    if (hi < 0x7F800000u) {
      float ut = expf(-__uint_as_float(hi)) * 0.999999f;  // conservative (Ek>=1)
      t = ((uint32_t)(ut * 8388608.0f)) << 9;
    }
    th[s] = t;
  }
  const float tiny = 1.1754943508222875e-38f;
  uint32_t row_c = (uint32_t)grow * 81920u;
  const float* Erow = Et + lrow * 128 + half * 64;
  int mxr = lrow & 31;
  uint32_t kbase = (uint32_t)(col0 + half * 64);

  for (int kk = 0; kk < 64; ++kk) {
    float Ek = Erow[kk ^ mxr];
    uint32_t base_c = row_c + kbase + (uint32_t)kk;
#pragma unroll
    for (int s = 0; s < N_SAMP; ++s) {
      uint32_t x0 = 0u, x1 = base_c + (uint32_t)s * 8192u;
      tf2x32(k0, k1, x0, x1);
      uint32_t bits = x0 ^ x1;
      if (bits >= th[s]) {
        float u = __uint_as_float(0x3f800000u | (bits >> 9)) - 1.0f;
        u = fmaxf(u, tiny);
        float wv = -logf(u) * Ek;            // exact r6 arithmetic
        unsigned long long p = ((unsigned long long)__float_as_uint(wv) << 32)
                             | (kbase + (uint32_t)kk);
        if (p < cw[s]) {
          cw[s] = p;
          float ut = expf(-wv) * 0.999999f;
          uint32_t nt = ((uint32_t)(ut * 8388608.0f)) << 9;
          th[s] = (nt > th[s]) ? nt : th[s]; // never loosen below snapshot screen
          improved |= (1 << s);
        }
      }
    }
  }
#pragma unroll
  for (int s = 0; s < N_SAMP; ++s)
    if (improved & (1 << s)) atomicMin(&cg[s], cw[s]);
}

// ---------------- fp32 NT GEMM (fallback, r6-proven) with E-epilogue ----------------
__global__ __launch_bounds__(256) void gemm_nt_kernel(const float* __restrict__ A,
                                                      const float* __restrict__ B,
                                                      const float* __restrict__ xx,
                                                      const float* __restrict__ ee,
                                                      float* __restrict__ E,
                                                      int ks, int KC) {
  __shared__ __align__(16) float Asf[32][68];
  __shared__ __align__(16) float Bsf[32][68];
  int tid = threadIdx.x;
  int row0 = blockIdx.y * 64;
  int colB0 = blockIdx.x * 64 + ks;
  int tx = tid & 15, ty = tid >> 4;
  float acc[4][4] = {};
  for (int d0 = 0; d0 < N_DIM; d0 += 32) {
#pragma unroll
    for (int r = 0; r < 2; ++r) {
      int c = tid + 256 * r;
      int m = c >> 3;
      int dv = (c & 7) << 2;
      const float4 va = *(const float4*)(A + (size_t)(row0 + m) * N_DIM + d0 + dv);
      Asf[dv + 0][m] = va.x; Asf[dv + 1][m] = va.y;
      Asf[dv + 2][m] = va.z; Asf[dv + 3][m] = va.w;
      const float4 vb = *(const float4*)(B + (size_t)(colB0 + m) * N_DIM + d0 + dv);
      Bsf[dv + 0][m] = vb.x; Bsf[dv + 1][m] = vb.y;
      Bsf[dv + 2][m] = vb.z; Bsf[dv + 3][m] = vb.w;
    }
    __syncthreads();
#pragma unroll
    for (int dd = 0; dd < 32; ++dd) {
      float4 a4 = *(const float4*)&Asf[dd][ty << 2];
      float4 b4 = *(const float4*)&Bsf[dd][tx << 2];
      float av[4] = {a4.x, a4.y, a4.z, a4.w};
      float bv[4] = {b4.x, b4.y, b4.z, b4.w};
#pragma unroll
      for (int i = 0; i < 4; ++i)
#pragma unroll
        for (int j = 0; j < 4; ++j)
          acc[i][j] = fmaf(av[i], bv[j], acc[i][j]);
    }
    __syncthreads();
  }
  const float inv_nt = 1.f / 8192.f;
  int colC0 = blockIdx.x * 64;
  float eev[4];
#pragma unroll
  for (int j = 0; j < 4; ++j) eev[j] = ee[ks + colC0 + (tx << 2) + j];
#pragma unroll
  for (int i = 0; i < 4; ++i) {
    int grow = row0 + (ty << 2) + i;
    float xxv = xx[grow];
    float4 v;
    v.x = expf((xxv + eev[0] - 2.0f * acc[i][0]) * inv_nt);
    v.y = expf((xxv + eev[1] - 2.0f * acc[i][1]) * inv_nt);
    v.z = expf((xxv + eev[2] - 2.0f * acc[i][2]) * inv_nt);
    v.w = expf((xxv + eev[3] - 2.0f * acc[i][3]) * inv_nt);
    *(float4*)(E + (size_t)grow * KC + colC0 + (tx << 2)) = v;
  }
}

// ---------------- fallback sampler: wave-shared champion + bits screen ----------------
__global__ __launch_bounds__(256) void sample_kernel(const float* __restrict__ E,
                                                     float* __restrict__ rmin,
                                                     int* __restrict__ ridx,
                                                     int ks, int KC,
                                                     uint32_t k0, uint32_t k1) {
  int lane = threadIdx.x & 63;
  int row = (int)((blockIdx.x * blockDim.x + threadIdx.x) >> 6);
  unsigned long long champ[N_SAMP];
  uint32_t th[N_SAMP];
#pragma unroll
  for (int s = 0; s < N_SAMP; ++s) { champ[s] = 0xFFFFFFFFFFFFFFFFULL; th[s] = 0u; }
  const float tiny = 1.1754943508222875e-38f;
  uint32_t row_c = (uint32_t)row * 81920u;
  const float* Erow = E + (size_t)row * KC;

  float Ek = Erow[lane];
  for (int kk = lane; kk < KC; kk += 64) {
    int nk = (kk + 64 < KC) ? kk + 64 : kk;
    float Ekn = Erow[nk];
    uint32_t k = (uint32_t)(ks + kk);
    uint32_t base_c = row_c + k;
#pragma unroll
    for (int s = 0; s < N_SAMP; ++s) {
      uint32_t x0 = 0u, x1 = base_c + (uint32_t)s * 8192u;
      tf2x32(k0, k1, x0, x1);
      uint32_t bits = x0 ^ x1;
      bool cand = (bits >= th[s]);
      if (__any(cand)) {
        float u = __uint_as_float(0x3f800000u | (bits >> 9)) - 1.0f;
        u = fmaxf(u, tiny);
        float wv = -logf(u) * Ek;
        unsigned long long p = cand
            ? (((unsigned long long)__float_as_uint(wv) << 32) | k)
            : 0xFFFFFFFFFFFFFFFFULL;
#pragma unroll
        for (int off = 1; off < 64; off <<= 1) {
          unsigned long long op = shfl_xor_u64(p, off);
          p = (op < p) ? op : p;
        }
        if (p < champ[s]) {
          champ[s] = p;
          float wmin = __uint_as_float((uint32_t)(p >> 32));
          float ut = expf(-wmin) * 0.999999f;
          th[s] = ((uint32_t)(ut * 8388608.0f)) << 9;
        }
      }
    }
    Ek = Ekn;
  }
#pragma unroll
  for (int s = 0; s < N_SAMP; ++s) {
    if (lane == 0) {
      float v = __uint_as_float((uint32_t)(champ[s] >> 32));
      int id = (int)(uint32_t)(champ[s] & 0xFFFFFFFFu);
      size_t p = (size_t)row * N_SAMP + s;
      if (v < rmin[p]) { rmin[p] = v; ridx[p] = id; }
    }
  }
}

// ---------------- gather + mean + straight-through (u64 champion version) ----------------
__global__ __launch_bounds__(256) void gather_kernel(const float* __restrict__ emb,
                                                     const unsigned long long* __restrict__ champ,
                                                     const float* __restrict__ x,
                                                     float* __restrict__ outq,
                                                     float* __restrict__ outs) {
  int lane = threadIdx.x & 63;
  int row = (int)((blockIdx.x * blockDim.x + threadIdx.x) >> 6);
  int idx[N_SAMP];
#pragma unroll
  for (int s = 0; s < N_SAMP; ++s)
    idx[s] = (int)(uint32_t)(champ[(size_t)row * N_SAMP + s] & 0xFFFFFFFFu);
  if (lane < N_SAMP) outs[row * N_SAMP + lane] = (float)idx[lane];
#pragma unroll
  for (int h = 0; h < 2; ++h) {
    int c = h * 256 + lane * 4;
    float4 sum = make_float4(0.f, 0.f, 0.f, 0.f);
#pragma unroll
    for (int s = 0; s < N_SAMP; ++s) {
      float4 e = *(const float4*)(emb + (size_t)idx[s] * N_DIM + c);
      sum.x += e.x; sum.y += e.y; sum.z += e.z; sum.w += e.w;
    }
    float4 xv = *(const float4*)(x + (size_t)row * N_DIM + c);
    float4 o;
    o.x = xv.x + (sum.x / 10.0f - xv.x);
    o.y = xv.y + (sum.y / 10.0f - xv.y);
    o.z = xv.z + (sum.z / 10.0f - xv.z);
    o.w = xv.w + (sum.w / 10.0f - xv.w);
    *(float4*)(outq + (size_t)row * N_DIM + c) = o;
  }
}

// ---------------- fallback gather (int ridx version) ----------------
__global__ __launch_bounds__(256) void gather_fb_kernel(const float* __restrict__ emb,
                                                        const int* __restrict__ ridx,
                                                        const float* __restrict__ x,
                                                        float* __restrict__ outq,
                                                        float* __restrict__ outs) {
  int lane = threadIdx.x & 63;
  int row = (int)((blockIdx.x * blockDim.x + threadIdx.x) >> 6);
  int idx[N_SAMP];
#pragma unroll
  for (int s = 0; s < N_SAMP; ++s) idx[s] = ridx[row * N_SAMP + s];
  if (lane < N_SAMP) outs[row * N_SAMP + lane] = (float)idx[lane];
#pragma unroll
  for (int h = 0; h < 2; ++h) {
    int c = h * 256 + lane * 4;
    float4 sum = make_float4(0.f, 0.f, 0.f, 0.f);
#pragma unroll
    for (int s = 0; s < N_SAMP; ++s) {
      float4 e = *(const float4*)(emb + (size_t)idx[s] * N_DIM + c);
      sum.x += e.x; sum.y += e.y; sum.z += e.z; sum.w += e.w;
    }
    float4 xv = *(const float4*)(x + (size_t)row * N_DIM + c);
    float4 o;
    o.x = xv.x + (sum.x / 10.0f - xv.x);
    o.y = xv.y + (sum.y / 10.0f - xv.y);
    o.z = xv.z + (sum.z / 10.0f - xv.z);
    o.w = xv.w + (sum.w / 10.0f - xv.w);
    *(float4*)(outq + (size_t)row * N_DIM + c) = o;
  }
}

extern "C" void kernel_launch(void* const* d_in, const int* in_sizes, int n_in,
                              void* d_out, int out_size, void* d_ws, size_t ws_size,
                              hipStream_t stream) {
  const float* x = (const float*)d_in[0];
  const float* emb = (const float*)d_in[1];
  float* out_q = (float*)d_out;
  float* out_s = out_q + (size_t)N_ROWS * N_DIM;

  const size_t split_u = (size_t)N_ROWS * GK;  // ushorts per split buffer
  const size_t fixed_f = (size_t)N_ROWS + N_TOK + 2 * (size_t)N_ROWS * N_SAMP;
  const size_t out_f = (size_t)N_ROWS * N_DIM + (size_t)N_ROWS * N_SAMP;

  uint32_t s0 = 0u, s1 = 1u;   // skey = fold_in(key(0), 1)
  tf2x32(0u, 0u, s0, s1);

  // ---- preferred path: fused bf16x2 MFMA GEMM + sampler (no E materialization) ----
  {
    size_t need = (size_t)(N_ROWS + N_TOK) * 4            // xx, ee
                + (size_t)N_ROWS * N_SAMP * 8             // champ u64
                + 2 * split_u * 2;                        // A2, B2
    if (need <= ws_size) {
      float* xx = (float*)d_ws;
      float* ee = xx + N_ROWS;
      unsigned long long* champ = (unsigned long long*)(ee + N_TOK);
      unsigned short* A2 = (unsigned short*)(champ + (size_t)N_ROWS * N_SAMP);
      unsigned short* B2 = A2 + split_u;

      rownorm_kernel<<<2048, 256, 0, stream>>>(x, xx);
      rownorm_kernel<<<2048, 256, 0, stream>>>(emb, ee);
      init_champ_kernel<<<(N_ROWS * N_SAMP + 255) / 256, 256, 0, stream>>>(champ);
      split_kernel<<<N_ROWS * 128 / 256, 256, 0, stream>>>(x, A2, 0);
      split_kernel<<<N_ROWS * 128 / 256, 256, 0, stream>>>(emb, B2, 1);
      fused_gemm_sample_kernel<<<dim3(64, 64), 256, 0, stream>>>(
          A2, B2, xx, ee, champ, s0, s1);
      gather_kernel<<<2048, 256, 0, stream>>>(emb, champ, x, out_q, out_s);
      return;
    }
  }

  // ---- fallback: fp32 path with adaptive placement (r6-proven) ----
  float *xx, *ee, *rmin, *E;
  int* ridx;
  int KC = 0;
  for (int c = 8192; c >= 64; c >>= 1) {
    if ((fixed_f + (size_t)N_ROWS * c) * 4 <= ws_size) { KC = c; break; }
  }
  if (KC) {
    xx = (float*)d_ws;
    ee = xx + N_ROWS;
    rmin = ee + N_TOK;
    ridx = (int*)(rmin + (size_t)N_ROWS * N_SAMP);
    E = (float*)(ridx + (size_t)N_ROWS * N_SAMP);
  } else if (fixed_f * 4 <= ws_size) {
    KC = 512;
    xx = (float*)d_ws;
    ee = xx + N_ROWS;
    rmin = ee + N_TOK;
    ridx = (int*)(rmin + (size_t)N_ROWS * N_SAMP);
    E = out_q;
  } else {
    KC = 256;
    E = out_q;
    float* tail = out_q + (out_f - fixed_f);
    xx = tail;
    ee = xx + N_ROWS;
    rmin = ee + N_TOK;
    ridx = (int*)(rmin + (size_t)N_ROWS * N_SAMP);
  }

  rownorm_kernel<<<2048, 256, 0, stream>>>(x, xx);
  rownorm_kernel<<<2048, 256, 0, stream>>>(emb, ee);
  init_state_kernel<<<(N_ROWS * N_SAMP + 255) / 256, 256, 0, stream>>>(rmin, ridx);
  for (int ks = 0; ks < N_TOK; ks += KC) {
    gemm_nt_kernel<<<dim3(KC / 64, N_ROWS / 64), 256, 0, stream>>>(x, emb, xx, ee, E, ks, KC);
    sample_kernel<<<2048, 256, 0, stream>>>(E, rmin, ridx, ks, KC, s0, s1);
  }
  gather_fb_kernel<<<2048, 256, 0, stream>>>(emb, ridx, x, out_q, out_s);
}